// Round 20
// baseline (291.373 us; speedup 1.0000x reference)
//
#include <hip/hip_runtime.h>
#include <hip/hip_bf16.h>

// Round 20: k_out_proj d-split (grid 8192, 64p x 64d per block, stats duplicated,
// XCD-paired for trih L2 reuse). k_ln wave-independent (r19), k_proj r17, k_tri r10.
// ws: lt[C][NP] | rt[C][NP] | xhp (frag) | trih[C][NP] (bf16) | warr | wcat2 | S,Tb

constexpr int TN = 512;
constexpr int TC = 128;
constexpr int TNP = TN * TN;
constexpr float TEPS = 1e-5f;

typedef __attribute__((ext_vector_type(8))) short s8b;   // 8 bf16
typedef __attribute__((ext_vector_type(4))) float f4;    // 4 fp32

__device__ __forceinline__ float wredsum(float v) {
#pragma unroll
    for (int off = 32; off > 0; off >>= 1) v += __shfl_xor(v, off);
    return v;
}
__device__ __forceinline__ float sigmoidf(float x) { return 1.0f / (1.0f + __expf(-x)); }
__device__ __forceinline__ unsigned short bfbits(float f) {
    __hip_bfloat16 h = __float2bfloat16(f);
    return *reinterpret_cast<unsigned short*>(&h);
}
__device__ __forceinline__ float bf2f(unsigned short u) {
    return __uint_as_float(((unsigned int)u) << 16);
}

// frag-unit layout (xhp global, LDS tiles, warr): unit(g = p>>4, kg = c>>5)
// of 512 ushorts; slot = ((c>>3)&3)*16 + (p&15); elem = c&7.

// -------- weight pre-convert/rearrange (wcat2: cnw-folded outp | gl) --------
extern "C" __global__ __launch_bounds__(256)
void k_wconv(const float* __restrict__ pw, const float* __restrict__ gw,
             const float* __restrict__ ow, const float* __restrict__ glw,
             const float* __restrict__ cnw,
             __hip_bfloat16* __restrict__ warr, __hip_bfloat16* __restrict__ wcat2)
{
    const int idx = blockIdx.x * 256 + threadIdx.x;
    if (idx < 65536) {
        const int j = idx & 7;
        const int slot = (idx >> 3) & 63;
        const int kg = (idx >> 9) & 3;
        const int rg = (idx >> 11) & 7;
        const int nc = idx >> 14;
        const int lh = slot & 15, lq = slot >> 4;
        const int row = rg * 16 + lh;
        const int k = kg * 32 + lq * 8 + j;
        const float v = (row < 64) ? pw[(nc * 64 + row) * TC + k]
                                   : gw[(nc * 64 + (row - 64)) * TC + k];
        warr[idx] = __float2bfloat16(v);
    } else if (idx < 98304) {
        const int j = idx - 65536;
        if (j < 16384) {
            const int c = j & 127;
            wcat2[j] = __float2bfloat16(cnw[c] * ow[j]);   // W' = cnw ⊙ outp_w
        } else {
            wcat2[j] = __float2bfloat16(glw[j - 16384]);
        }
    }
}

// -------- S_d / Tb_d for the affine-folded LN --------
extern "C" __global__ __launch_bounds__(128)
void k_sdt(const float* __restrict__ ow, const float* __restrict__ cnw,
           const float* __restrict__ cnb, const float* __restrict__ outp_b,
           float* __restrict__ Svec, float* __restrict__ Tbvec)
{
    const int d = threadIdx.x;
    float S = 0.f, T = 0.f;
    for (int c = 0; c < TC; ++c) {
        const float w = ow[d * TC + c];
        S += cnw[c] * w;
        T += cnb[c] * w;
    }
    Svec[d] = S;
    Tbvec[d] = T + outp_b[d];
}

// -------- Kernel A1: LayerNorm -> xh_perm; wave-independent (r19) --------
extern "C" __global__ __launch_bounds__(256)
void k_ln(const float* __restrict__ act, const float* __restrict__ lnw,
          const float* __restrict__ lnb, __hip_bfloat16* __restrict__ xhp)
{
    __shared__ __align__(16) unsigned short t16[4][16 * 136];   // per-wave tiles
    const int t = threadIdx.x, lane = t & 63, w = t >> 6;
    const int P0 = blockIdx.x * 64 + w * 16;
    const float2 wv = ((const float2*)lnw)[lane];
    const float2 bv = ((const float2*)lnb)[lane];
    unsigned short* xb = (unsigned short*)xhp;

#pragma unroll 4
    for (int q = 0; q < 16; ++q) {
        const int p = P0 + q;
        const float2 a = ((const float2*)(act + (size_t)p * TC))[lane];
        const float mu = wredsum(a.x + a.y) * (1.0f / 128.0f);
        const float d0 = a.x - mu, d1 = a.y - mu;
        const float var = wredsum(d0 * d0 + d1 * d1) * (1.0f / 128.0f);
        const float rs = rsqrtf(var + TEPS);
        ushort2 o;
        o.x = bfbits(d0 * rs * wv.x + bv.x);
        o.y = bfbits(d1 * rs * wv.y + bv.y);
        *(ushort2*)&t16[w][q * 136 + lane * 2] = o;
    }
    {
        const int lq = lane >> 4, lh = lane & 15;
        const size_t g = (size_t)(P0 >> 4);
#pragma unroll
        for (int kg = 0; kg < 4; ++kg) {
            const s8b v = *(const s8b*)&t16[w][lh * 136 + kg * 32 + lq * 8];
            *(s8b*)(xb + g * 2048 + kg * 512 + (size_t)lane * 8) = v;
        }
    }
}

// -------- Kernel A2: MFMA proj+gate GEMM (r17 form) --------
extern "C" __global__ __launch_bounds__(256)
void k_proj(const __hip_bfloat16* __restrict__ xhp, const float* __restrict__ mask,
            const __hip_bfloat16* __restrict__ warr,
            const float* __restrict__ proj_b, const float* __restrict__ gate_b,
            __hip_bfloat16* __restrict__ lt, __hip_bfloat16* __restrict__ rt)
{
    __shared__ __align__(16) unsigned short Xls[128 * TC];   // 32 KB, frag units
    __shared__ float msk[128];
    unsigned short* tls = Xls;   // 64x134 transpose tile aliased after MFMA

    const int t = threadIdx.x, lane = t & 63, w = t >> 6;
    const int lh = lane & 15, lq = lane >> 4;

    const int bid = blockIdx.x;
    const int work = (bid & 7) * 1024 + (bid >> 3);
    const int pt = work >> 2, dt = work & 3;
    const int P0 = pt * 128;

    const unsigned short* xb = (const unsigned short*)xhp;
    const unsigned short* wbc = (const unsigned short*)warr + (size_t)dt * 16384;

    if (t < 128) msk[t] = mask[P0 + t];

    const int wm = w >> 1, wn = w & 1;

#pragma unroll
    for (int s = 0; s < 8; ++s) {
        const int u = w * 8 + s;
        const size_t gu = ((size_t)(P0 >> 4) + (u >> 2)) * 4 + (u & 3);
        __builtin_amdgcn_global_load_lds(
            (const __attribute__((address_space(1))) unsigned*)(xb + gu * 512 + (size_t)lane * 8),
            (__attribute__((address_space(3))) unsigned*)&Xls[u * 512], 16, 0, 0);
    }

    s8b bc[4], bn[4];
#pragma unroll
    for (int nd = 0; nd < 2; ++nd) {
        bc[nd]     = *(const s8b*)(wbc + (size_t)(((wn * 2 + nd) * 4) + 0) * 512 + lane * 8);
        bc[2 + nd] = *(const s8b*)(wbc + (size_t)(((4 + wn * 2 + nd) * 4) + 0) * 512 + lane * 8);
    }
    __syncthreads();

    f4 acc[4][4];
#pragma unroll
    for (int mi = 0; mi < 4; ++mi)
#pragma unroll
        for (int ni = 0; ni < 4; ++ni)
            acc[mi][ni] = (f4){0.f, 0.f, 0.f, 0.f};

#pragma unroll
    for (int kg = 0; kg < 4; ++kg) {
        if (kg < 3) {
#pragma unroll
            for (int nd = 0; nd < 2; ++nd) {
                bn[nd]     = *(const s8b*)(wbc + (size_t)(((wn * 2 + nd) * 4) + kg + 1) * 512 + lane * 8);
                bn[2 + nd] = *(const s8b*)(wbc + (size_t)(((4 + wn * 2 + nd) * 4) + kg + 1) * 512 + lane * 8);
            }
        }
        s8b af[4];
#pragma unroll
        for (int mi = 0; mi < 4; ++mi)
            af[mi] = *(const s8b*)&Xls[(((wm * 4 + mi) * 4) + kg) * 512 + lane * 8];
#pragma unroll
        for (int mi = 0; mi < 4; ++mi)
#pragma unroll
            for (int ni = 0; ni < 4; ++ni)
                acc[mi][ni] = __builtin_amdgcn_mfma_f32_16x16x32_bf16(
                    af[mi], bc[ni], acc[mi][ni], 0, 0, 0);
        if (kg < 3) {
#pragma unroll
            for (int ni = 0; ni < 4; ++ni) bc[ni] = bn[ni];
        }
    }
    __syncthreads();

#pragma unroll
    for (int mi = 0; mi < 4; ++mi)
#pragma unroll
        for (int nd = 0; nd < 2; ++nd) {
            const int dl = wn * 32 + nd * 16 + lh;
            const float pbv = proj_b[dt * 64 + dl];
            const float gbv = gate_b[dt * 64 + dl];
            const f4 P = acc[mi][nd];
            const f4 G = acc[mi][2 + nd];
            const int pbase = wm * 64 + mi * 16 + lq * 4;
            float v[4];
#pragma unroll
            for (int r = 0; r < 4; ++r)
                v[r] = msk[pbase + r] * (P[r] + pbv) * sigmoidf(G[r] + gbv);
            ushort2 u01, u23;
            u01.x = bfbits(v[0]); u01.y = bfbits(v[1]);
            u23.x = bfbits(v[2]); u23.y = bfbits(v[3]);
            *(ushort2*)&tls[dl * 134 + pbase]     = u01;
            *(ushort2*)&tls[dl * 134 + pbase + 2] = u23;
        }
    __syncthreads();

    {
        __hip_bfloat16* dst0 = (dt < 2) ? lt + (size_t)(dt * 64) * TNP
                                        : rt + (size_t)((dt - 2) * 64) * TNP;
#pragma unroll
        for (int rr = 0; rr < 16; ++rr) {
            const int dl = w * 16 + rr;
            const ushort2 v = *(const ushort2*)&tls[dl * 134 + lane * 2];
            *(ushort2*)((unsigned short*)(dst0 + (size_t)dl * TNP) + P0 + lane * 2) = v;
        }
    }
}

// -------- Kernel B: per-c NT-GEMM (r10 single-stage version) --------
extern "C" __global__ __launch_bounds__(256)
void k_tri_mfma(const __hip_bfloat16* __restrict__ lt,
                const __hip_bfloat16* __restrict__ rt,
                __hip_bfloat16* __restrict__ trih)
{
    __shared__ __align__(16) char smem[128 * 136 * 2];
    __hip_bfloat16* Als = (__hip_bfloat16*)smem;
    __hip_bfloat16* Bls = (__hip_bfloat16*)(smem + 8192);
    unsigned short* Cls = (unsigned short*)smem;

    const int bid = blockIdx.x;
    const int work = (bid & 7) * 256 + (bid >> 3);
    const int c = work >> 4, tt = work & 15;
    const int i0 = (tt >> 2) * 128, j0 = (tt & 3) * 128;

    const int t = threadIdx.x;
    const int w = t >> 6, lane = t & 63;
    const int wm = w >> 1, wn = w & 1;
    const int lh = lane & 15, lq = lane >> 4;

    const size_t cbase = (size_t)c * TNP;
    const int srow = lane >> 2;
    const int scol = (lane & 3) * 8;

    f4 acc[4][4];
#pragma unroll
    for (int mi = 0; mi < 4; ++mi)
#pragma unroll
        for (int ni = 0; ni < 4; ++ni)
            acc[mi][ni] = (f4){0.f, 0.f, 0.f, 0.f};

    for (int k0 = 0; k0 < TN; k0 += 32) {
        __syncthreads();
#pragma unroll
        for (int s = 0; s < 2; ++s) {
            const int r0 = w * 32 + s * 16;
            const __hip_bfloat16* ga = lt + cbase + (size_t)(i0 + r0 + srow) * TN + k0 + scol;
            const __hip_bfloat16* gbp = rt + cbase + (size_t)(j0 + r0 + srow) * TN + k0 + scol;
            __builtin_amdgcn_global_load_lds(
                (const __attribute__((address_space(1))) unsigned*)ga,
                (__attribute__((address_space(3))) unsigned*)&Als[r0 * 32], 16, 0, 0);
            __builtin_amdgcn_global_load_lds(
                (const __attribute__((address_space(1))) unsigned*)gbp,
                (__attribute__((address_space(3))) unsigned*)&Bls[r0 * 32], 16, 0, 0);
        }
        __syncthreads();

        s8b afr[4], bfr[4];
#pragma unroll
        for (int mi = 0; mi < 4; ++mi)
            afr[mi] = *(const s8b*)&Als[(wm * 64 + mi * 16 + lh) * 32 + lq * 8];
#pragma unroll
        for (int ni = 0; ni < 4; ++ni)
            bfr[ni] = *(const s8b*)&Bls[(wn * 64 + ni * 16 + lh) * 32 + lq * 8];
#pragma unroll
        for (int mi = 0; mi < 4; ++mi)
#pragma unroll
            for (int ni = 0; ni < 4; ++ni)
                acc[mi][ni] = __builtin_amdgcn_mfma_f32_16x16x32_bf16(
                    afr[mi], bfr[ni], acc[mi][ni], 0, 0, 0);
    }

    __syncthreads();
#pragma unroll
    for (int mi = 0; mi < 4; ++mi)
#pragma unroll
        for (int ni = 0; ni < 4; ++ni) {
            const f4 v = acc[mi][ni];
            const int jl = wn * 64 + ni * 16 + lh;
#pragma unroll
            for (int r = 0; r < 4; ++r) {
                const int il = wm * 64 + mi * 16 + lq * 4 + r;
                Cls[il * 136 + jl] = bfbits(v[r]);
            }
        }
    __syncthreads();
    {
        unsigned short* ob = (unsigned short*)trih + cbase;
#pragma unroll
        for (int qq = 0; qq < 8; ++qq) {
            const int row = qq * 16 + (t >> 4);
            const int c16 = t & 15;
            const s8b v = *(const s8b*)&Cls[row * 136 + c16 * 8];
            *(s8b*)&ob[(size_t)(i0 + row) * TN + j0 + c16 * 8] = v;
        }
    }
}

// -------- Kernel C: d-split (64p x 64d per block, grid 8192, XCD-paired) -------
constexpr int PB = 64;

extern "C" __global__ __launch_bounds__(256)
void k_out_proj(const __hip_bfloat16* __restrict__ trih,
                const __hip_bfloat16* __restrict__ xhp,
                const __hip_bfloat16* __restrict__ wcat2,
                const float* __restrict__ Svec, const float* __restrict__ Tbvec,
                const float* __restrict__ gl_b,
                float* __restrict__ outb)
{
    __shared__ __align__(16) unsigned short yfr[PB * TC];   // 16 KB frag units
    __shared__ float2 sred[4][PB];                           // 2 KB partials
    __shared__ float2 stats[PB];                             // (mu, rs)

    const int t = threadIdx.x, lane = t & 63, w = t >> 6;
    const int lh = lane & 15, lq = lane >> 4;

    // grid 8192 = 8 XCDs x 1024; dh-pair consecutive within XCD -> trih L2 reuse
    const int bid = blockIdx.x;
    const int work = (bid & 7) * 1024 + (bid >> 3);
    const int pt = work >> 1, dh = work & 1;
    const int P0 = pt * PB;

    const unsigned short* tb = (const unsigned short*)trih;
    const unsigned short* xb = (const unsigned short*)xhp;
    const unsigned short* wb = (const unsigned short*)wcat2;

    // ---- prefetch kg=0 H-frags (latency flies under stage+stats) ----
    s8b ahc[4];
#pragma unroll
    for (int mi = 0; mi < 4; ++mi)
        ahc[mi] = *(const s8b*)(xb + (size_t)((P0 >> 4) + mi) * 2048 + (size_t)lane * 8);

    // ---- fused stage+stats: lane = p, wave w owns c in [32w,32w+32) ----
    {
        const int p = lane;
        const int ub = (p >> 4) * 4 + w;
        const int sl = p & 15;
        float s = 0.f, s2 = 0.f;
#pragma unroll
        for (int q = 0; q < 4; ++q) {
            unsigned short tmp[8];
#pragma unroll
            for (int j = 0; j < 8; ++j) {
                const int c = w * 32 + q * 8 + j;
                tmp[j] = tb[(size_t)c * TNP + P0 + p];
                const float f = bf2f(tmp[j]);
                s += f; s2 += f * f;
            }
            *(s8b*)&yfr[ub * 512 + (q * 16 + sl) * 8] = *(const s8b*)tmp;
        }
        sred[w][p] = make_float2(s, s2);
    }
    __syncthreads();
    if (t < PB) {
        float s = 0.f, s2 = 0.f;
#pragma unroll
        for (int g = 0; g < 4; ++g) {
            const float2 v = sred[g][t];
            s += v.x; s2 += v.y;
        }
        const float mu = s * (1.0f / 128.0f);
        const float var = s2 * (1.0f / 128.0f) - mu * mu;
        stats[t] = make_float2(mu, rsqrtf(var + TEPS));
    }
    __syncthreads();

    // ---- dual GEMM: wave w owns outp dim-group dh*64+w*16 and matching gl ----
    const int dO = dh * 64 + w * 16;
    const int dG = 128 + dO;

    f4 acc[4][2];   // ni 0 = outp(Y·W'), 1 = gl(H)
#pragma unroll
    for (int mi = 0; mi < 4; ++mi)
#pragma unroll
        for (int ni = 0; ni < 2; ++ni)
            acc[mi][ni] = (f4){0.f, 0.f, 0.f, 0.f};

#pragma unroll
    for (int kg = 0; kg < 4; ++kg) {
        s8b ahn[4];
        if (kg < 3) {
#pragma unroll
            for (int mi = 0; mi < 4; ++mi)
                ahn[mi] = *(const s8b*)(xb + (size_t)((P0 >> 4) + mi) * 2048
                                           + (kg + 1) * 512 + (size_t)lane * 8);
        }
        const s8b bo = *(const s8b*)(wb + (dO + lh) * TC + kg * 32 + lq * 8);
        const s8b bg = *(const s8b*)(wb + (dG + lh) * TC + kg * 32 + lq * 8);
        s8b ay[4];
#pragma unroll
        for (int mi = 0; mi < 4; ++mi)
            ay[mi] = *(const s8b*)&yfr[(mi * 4 + kg) * 512 + lane * 8];
#pragma unroll
        for (int mi = 0; mi < 4; ++mi) {
            acc[mi][0] = __builtin_amdgcn_mfma_f32_16x16x32_bf16(
                ay[mi], bo, acc[mi][0], 0, 0, 0);
            acc[mi][1] = __builtin_amdgcn_mfma_f32_16x16x32_bf16(
                ahc[mi], bg, acc[mi][1], 0, 0, 0);
        }
        if (kg < 3) {
#pragma unroll
            for (int mi = 0; mi < 4; ++mi) ahc[mi] = ahn[mi];
        }
    }

    // ---- epilogue: out = (rs*G - rs*mu*S_d + Tb_d) * sigmoid(Gl + gl_b) ----
    const int d = dO + lh;
    const float Sd  = Svec[d];
    const float Tbd = Tbvec[d];
    const float glb = gl_b[d];
#pragma unroll
    for (int mi = 0; mi < 4; ++mi) {
        const f4 G  = acc[mi][0];
        const f4 Gg = acc[mi][1];
#pragma unroll
        for (int r = 0; r < 4; ++r) {
            const int ploc = mi * 16 + lq * 4 + r;
            const float2 st = stats[ploc];
            const float o = st.y * G[r] - st.y * st.x * Sd + Tbd;
            outb[(size_t)(P0 + ploc) * TC + d] = o * sigmoidf(Gg[r] + glb);
        }
    }
}

extern "C" void kernel_launch(void* const* d_in, const int* in_sizes, int n_in,
                              void* d_out, int out_size, void* d_ws, size_t ws_size,
                              hipStream_t stream)
{
    const float* act    = (const float*)d_in[0];
    const float* mask   = (const float*)d_in[1];
    const float* lnw    = (const float*)d_in[2];
    const float* lnb    = (const float*)d_in[3];
    const float* proj_w = (const float*)d_in[4];
    const float* proj_b = (const float*)d_in[5];
    const float* gate_w = (const float*)d_in[6];
    const float* gate_b = (const float*)d_in[7];
    const float* cnw    = (const float*)d_in[8];
    const float* cnb    = (const float*)d_in[9];
    const float* outp_w = (const float*)d_in[10];
    const float* outp_b = (const float*)d_in[11];
    const float* gl_w   = (const float*)d_in[12];
    const float* gl_b   = (const float*)d_in[13];

    __hip_bfloat16* lt   = (__hip_bfloat16*)d_ws;
    __hip_bfloat16* rt   = lt + (size_t)TC * TNP;
    __hip_bfloat16* xhp  = rt + (size_t)TC * TNP;
    __hip_bfloat16* trih = xhp + (size_t)TNP * TC;
    __hip_bfloat16* warr = trih + (size_t)TC * TNP;
    __hip_bfloat16* wcat2 = warr + 4 * 128 * TC;
    float* Svec  = (float*)(wcat2 + 2 * TC * TC);
    float* Tbvec = Svec + TC;
    float* out = (float*)d_out;

    k_wconv<<<384, 256, 0, stream>>>(proj_w, gate_w, outp_w, gl_w, cnw, warr, wcat2);
    k_sdt<<<1, 128, 0, stream>>>(outp_w, cnw, cnb, outp_b, Svec, Tbvec);
    k_ln<<<TNP / 64, 256, 0, stream>>>(act, lnw, lnb, xhp);
    k_proj<<<8192, 256, 0, stream>>>(xhp, mask, warr, proj_b, gate_b, lt, rt);
    k_tri_mfma<<<2048, 256, 0, stream>>>(lt, rt, trih);
    k_out_proj<<<8192, 256, 0, stream>>>(trih, xhp, wcat2, Svec, Tbvec,
                                         gl_b, out);
}

// Round 21
// 286.035 us; speedup vs baseline: 1.0187x; 1.0187x over previous
//
#include <hip/hip_runtime.h>
#include <hip/hip_bf16.h>

// Round 21: revert to r17-best; kernel C stage+stats widened (ushort2 p-pair
// reads, 256B/instr, halved per-lane stats chains, 8-way sred combine).
// ws: lt[C][NP] | rt[C][NP] | xhp (frag) | trih[C][NP] (bf16) | warr | wcat2 | S,Tb

constexpr int TN = 512;
constexpr int TC = 128;
constexpr int TNP = TN * TN;
constexpr float TEPS = 1e-5f;

typedef __attribute__((ext_vector_type(8))) short s8b;   // 8 bf16
typedef __attribute__((ext_vector_type(4))) float f4;    // 4 fp32

__device__ __forceinline__ float wredsum(float v) {
#pragma unroll
    for (int off = 32; off > 0; off >>= 1) v += __shfl_xor(v, off);
    return v;
}
__device__ __forceinline__ float sigmoidf(float x) { return 1.0f / (1.0f + __expf(-x)); }
__device__ __forceinline__ unsigned short bfbits(float f) {
    __hip_bfloat16 h = __float2bfloat16(f);
    return *reinterpret_cast<unsigned short*>(&h);
}
__device__ __forceinline__ float bf2f(unsigned short u) {
    return __uint_as_float(((unsigned int)u) << 16);
}

// frag-unit layout (xhp global, LDS tiles, warr): unit(g = p>>4, kg = c>>5)
// of 512 ushorts; slot = ((c>>3)&3)*16 + (p&15); elem = c&7.

// -------- weight pre-convert/rearrange (wcat2: cnw-folded outp | gl) --------
extern "C" __global__ __launch_bounds__(256)
void k_wconv(const float* __restrict__ pw, const float* __restrict__ gw,
             const float* __restrict__ ow, const float* __restrict__ glw,
             const float* __restrict__ cnw,
             __hip_bfloat16* __restrict__ warr, __hip_bfloat16* __restrict__ wcat2)
{
    const int idx = blockIdx.x * 256 + threadIdx.x;
    if (idx < 65536) {
        const int j = idx & 7;
        const int slot = (idx >> 3) & 63;
        const int kg = (idx >> 9) & 3;
        const int rg = (idx >> 11) & 7;
        const int nc = idx >> 14;
        const int lh = slot & 15, lq = slot >> 4;
        const int row = rg * 16 + lh;
        const int k = kg * 32 + lq * 8 + j;
        const float v = (row < 64) ? pw[(nc * 64 + row) * TC + k]
                                   : gw[(nc * 64 + (row - 64)) * TC + k];
        warr[idx] = __float2bfloat16(v);
    } else if (idx < 98304) {
        const int j = idx - 65536;
        if (j < 16384) {
            const int c = j & 127;
            wcat2[j] = __float2bfloat16(cnw[c] * ow[j]);   // W' = cnw ⊙ outp_w
        } else {
            wcat2[j] = __float2bfloat16(glw[j - 16384]);
        }
    }
}

// -------- S_d / Tb_d for the affine-folded LN --------
extern "C" __global__ __launch_bounds__(128)
void k_sdt(const float* __restrict__ ow, const float* __restrict__ cnw,
           const float* __restrict__ cnb, const float* __restrict__ outp_b,
           float* __restrict__ Svec, float* __restrict__ Tbvec)
{
    const int d = threadIdx.x;
    float S = 0.f, T = 0.f;
    for (int c = 0; c < TC; ++c) {
        const float w = ow[d * TC + c];
        S += cnw[c] * w;
        T += cnb[c] * w;
    }
    Svec[d] = S;
    Tbvec[d] = T + outp_b[d];
}

// -------- Kernel A1: LayerNorm -> xh_perm; wave-independent (r19) --------
extern "C" __global__ __launch_bounds__(256)
void k_ln(const float* __restrict__ act, const float* __restrict__ lnw,
          const float* __restrict__ lnb, __hip_bfloat16* __restrict__ xhp)
{
    __shared__ __align__(16) unsigned short t16[4][16 * 136];
    const int t = threadIdx.x, lane = t & 63, w = t >> 6;
    const int P0 = blockIdx.x * 64 + w * 16;
    const float2 wv = ((const float2*)lnw)[lane];
    const float2 bv = ((const float2*)lnb)[lane];
    unsigned short* xb = (unsigned short*)xhp;

#pragma unroll 4
    for (int q = 0; q < 16; ++q) {
        const int p = P0 + q;
        const float2 a = ((const float2*)(act + (size_t)p * TC))[lane];
        const float mu = wredsum(a.x + a.y) * (1.0f / 128.0f);
        const float d0 = a.x - mu, d1 = a.y - mu;
        const float var = wredsum(d0 * d0 + d1 * d1) * (1.0f / 128.0f);
        const float rs = rsqrtf(var + TEPS);
        ushort2 o;
        o.x = bfbits(d0 * rs * wv.x + bv.x);
        o.y = bfbits(d1 * rs * wv.y + bv.y);
        *(ushort2*)&t16[w][q * 136 + lane * 2] = o;
    }
    {
        const int lq = lane >> 4, lh = lane & 15;
        const size_t g = (size_t)(P0 >> 4);
#pragma unroll
        for (int kg = 0; kg < 4; ++kg) {
            const s8b v = *(const s8b*)&t16[w][lh * 136 + kg * 32 + lq * 8];
            *(s8b*)(xb + g * 2048 + kg * 512 + (size_t)lane * 8) = v;
        }
    }
}

// -------- Kernel A2: MFMA proj+gate GEMM (r17 form) --------
extern "C" __global__ __launch_bounds__(256)
void k_proj(const __hip_bfloat16* __restrict__ xhp, const float* __restrict__ mask,
            const __hip_bfloat16* __restrict__ warr,
            const float* __restrict__ proj_b, const float* __restrict__ gate_b,
            __hip_bfloat16* __restrict__ lt, __hip_bfloat16* __restrict__ rt)
{
    __shared__ __align__(16) unsigned short Xls[128 * TC];   // 32 KB, frag units
    __shared__ float msk[128];
    unsigned short* tls = Xls;   // 64x134 transpose tile aliased after MFMA

    const int t = threadIdx.x, lane = t & 63, w = t >> 6;
    const int lh = lane & 15, lq = lane >> 4;

    const int bid = blockIdx.x;
    const int work = (bid & 7) * 1024 + (bid >> 3);
    const int pt = work >> 2, dt = work & 3;
    const int P0 = pt * 128;

    const unsigned short* xb = (const unsigned short*)xhp;
    const unsigned short* wbc = (const unsigned short*)warr + (size_t)dt * 16384;

    if (t < 128) msk[t] = mask[P0 + t];

    const int wm = w >> 1, wn = w & 1;

#pragma unroll
    for (int s = 0; s < 8; ++s) {
        const int u = w * 8 + s;
        const size_t gu = ((size_t)(P0 >> 4) + (u >> 2)) * 4 + (u & 3);
        __builtin_amdgcn_global_load_lds(
            (const __attribute__((address_space(1))) unsigned*)(xb + gu * 512 + (size_t)lane * 8),
            (__attribute__((address_space(3))) unsigned*)&Xls[u * 512], 16, 0, 0);
    }

    s8b bc[4], bn[4];
#pragma unroll
    for (int nd = 0; nd < 2; ++nd) {
        bc[nd]     = *(const s8b*)(wbc + (size_t)(((wn * 2 + nd) * 4) + 0) * 512 + lane * 8);
        bc[2 + nd] = *(const s8b*)(wbc + (size_t)(((4 + wn * 2 + nd) * 4) + 0) * 512 + lane * 8);
    }
    __syncthreads();

    f4 acc[4][4];
#pragma unroll
    for (int mi = 0; mi < 4; ++mi)
#pragma unroll
        for (int ni = 0; ni < 4; ++ni)
            acc[mi][ni] = (f4){0.f, 0.f, 0.f, 0.f};

#pragma unroll
    for (int kg = 0; kg < 4; ++kg) {
        if (kg < 3) {
#pragma unroll
            for (int nd = 0; nd < 2; ++nd) {
                bn[nd]     = *(const s8b*)(wbc + (size_t)(((wn * 2 + nd) * 4) + kg + 1) * 512 + lane * 8);
                bn[2 + nd] = *(const s8b*)(wbc + (size_t)(((4 + wn * 2 + nd) * 4) + kg + 1) * 512 + lane * 8);
            }
        }
        s8b af[4];
#pragma unroll
        for (int mi = 0; mi < 4; ++mi)
            af[mi] = *(const s8b*)&Xls[(((wm * 4 + mi) * 4) + kg) * 512 + lane * 8];
#pragma unroll
        for (int mi = 0; mi < 4; ++mi)
#pragma unroll
            for (int ni = 0; ni < 4; ++ni)
                acc[mi][ni] = __builtin_amdgcn_mfma_f32_16x16x32_bf16(
                    af[mi], bc[ni], acc[mi][ni], 0, 0, 0);
        if (kg < 3) {
#pragma unroll
            for (int ni = 0; ni < 4; ++ni) bc[ni] = bn[ni];
        }
    }
    __syncthreads();

#pragma unroll
    for (int mi = 0; mi < 4; ++mi)
#pragma unroll
        for (int nd = 0; nd < 2; ++nd) {
            const int dl = wn * 32 + nd * 16 + lh;
            const float pbv = proj_b[dt * 64 + dl];
            const float gbv = gate_b[dt * 64 + dl];
            const f4 P = acc[mi][nd];
            const f4 G = acc[mi][2 + nd];
            const int pbase = wm * 64 + mi * 16 + lq * 4;
            float v[4];
#pragma unroll
            for (int r = 0; r < 4; ++r)
                v[r] = msk[pbase + r] * (P[r] + pbv) * sigmoidf(G[r] + gbv);
            ushort2 u01, u23;
            u01.x = bfbits(v[0]); u01.y = bfbits(v[1]);
            u23.x = bfbits(v[2]); u23.y = bfbits(v[3]);
            *(ushort2*)&tls[dl * 134 + pbase]     = u01;
            *(ushort2*)&tls[dl * 134 + pbase + 2] = u23;
        }
    __syncthreads();

    {
        __hip_bfloat16* dst0 = (dt < 2) ? lt + (size_t)(dt * 64) * TNP
                                        : rt + (size_t)((dt - 2) * 64) * TNP;
#pragma unroll
        for (int rr = 0; rr < 16; ++rr) {
            const int dl = w * 16 + rr;
            const ushort2 v = *(const ushort2*)&tls[dl * 134 + lane * 2];
            *(ushort2*)((unsigned short*)(dst0 + (size_t)dl * TNP) + P0 + lane * 2) = v;
        }
    }
}

// -------- Kernel B: per-c NT-GEMM (r10 single-stage version) --------
extern "C" __global__ __launch_bounds__(256)
void k_tri_mfma(const __hip_bfloat16* __restrict__ lt,
                const __hip_bfloat16* __restrict__ rt,
                __hip_bfloat16* __restrict__ trih)
{
    __shared__ __align__(16) char smem[128 * 136 * 2];
    __hip_bfloat16* Als = (__hip_bfloat16*)smem;
    __hip_bfloat16* Bls = (__hip_bfloat16*)(smem + 8192);
    unsigned short* Cls = (unsigned short*)smem;

    const int bid = blockIdx.x;
    const int work = (bid & 7) * 256 + (bid >> 3);
    const int c = work >> 4, tt = work & 15;
    const int i0 = (tt >> 2) * 128, j0 = (tt & 3) * 128;

    const int t = threadIdx.x;
    const int w = t >> 6, lane = t & 63;
    const int wm = w >> 1, wn = w & 1;
    const int lh = lane & 15, lq = lane >> 4;

    const size_t cbase = (size_t)c * TNP;
    const int srow = lane >> 2;
    const int scol = (lane & 3) * 8;

    f4 acc[4][4];
#pragma unroll
    for (int mi = 0; mi < 4; ++mi)
#pragma unroll
        for (int ni = 0; ni < 4; ++ni)
            acc[mi][ni] = (f4){0.f, 0.f, 0.f, 0.f};

    for (int k0 = 0; k0 < TN; k0 += 32) {
        __syncthreads();
#pragma unroll
        for (int s = 0; s < 2; ++s) {
            const int r0 = w * 32 + s * 16;
            const __hip_bfloat16* ga = lt + cbase + (size_t)(i0 + r0 + srow) * TN + k0 + scol;
            const __hip_bfloat16* gbp = rt + cbase + (size_t)(j0 + r0 + srow) * TN + k0 + scol;
            __builtin_amdgcn_global_load_lds(
                (const __attribute__((address_space(1))) unsigned*)ga,
                (__attribute__((address_space(3))) unsigned*)&Als[r0 * 32], 16, 0, 0);
            __builtin_amdgcn_global_load_lds(
                (const __attribute__((address_space(1))) unsigned*)gbp,
                (__attribute__((address_space(3))) unsigned*)&Bls[r0 * 32], 16, 0, 0);
        }
        __syncthreads();

        s8b afr[4], bfr[4];
#pragma unroll
        for (int mi = 0; mi < 4; ++mi)
            afr[mi] = *(const s8b*)&Als[(wm * 64 + mi * 16 + lh) * 32 + lq * 8];
#pragma unroll
        for (int ni = 0; ni < 4; ++ni)
            bfr[ni] = *(const s8b*)&Bls[(wn * 64 + ni * 16 + lh) * 32 + lq * 8];
#pragma unroll
        for (int mi = 0; mi < 4; ++mi)
#pragma unroll
            for (int ni = 0; ni < 4; ++ni)
                acc[mi][ni] = __builtin_amdgcn_mfma_f32_16x16x32_bf16(
                    afr[mi], bfr[ni], acc[mi][ni], 0, 0, 0);
    }

    __syncthreads();
#pragma unroll
    for (int mi = 0; mi < 4; ++mi)
#pragma unroll
        for (int ni = 0; ni < 4; ++ni) {
            const f4 v = acc[mi][ni];
            const int jl = wn * 64 + ni * 16 + lh;
#pragma unroll
            for (int r = 0; r < 4; ++r) {
                const int il = wm * 64 + mi * 16 + lq * 4 + r;
                Cls[il * 136 + jl] = bfbits(v[r]);
            }
        }
    __syncthreads();
    {
        unsigned short* ob = (unsigned short*)trih + cbase;
#pragma unroll
        for (int qq = 0; qq < 8; ++qq) {
            const int row = qq * 16 + (t >> 4);
            const int c16 = t & 15;
            const s8b v = *(const s8b*)&Cls[row * 136 + c16 * 8];
            *(s8b*)&ob[(size_t)(i0 + row) * TN + j0 + c16 * 8] = v;
        }
    }
}

// -------- Kernel C: affine-folded LN + MFMA; widened stage+stats --------
constexpr int PB = 64;

extern "C" __global__ __launch_bounds__(256)
void k_out_proj(const __hip_bfloat16* __restrict__ trih,
                const __hip_bfloat16* __restrict__ xhp,
                const __hip_bfloat16* __restrict__ wcat2,
                const float* __restrict__ Svec, const float* __restrict__ Tbvec,
                const float* __restrict__ gl_b,
                float* __restrict__ outb)
{
    __shared__ __align__(16) unsigned short yfr[PB * TC];   // 16 KB frag units
    __shared__ float2 sred[8][PB];                           // 4 KB partials
    __shared__ float2 stats[PB];                             // (mu, rs)

    const int t = threadIdx.x, lane = t & 63, w = t >> 6;
    const int lh = lane & 15, lq = lane >> 4;
    const int P0 = blockIdx.x * PB;
    const unsigned short* tb = (const unsigned short*)trih;
    const unsigned short* xb = (const unsigned short*)xhp;
    const unsigned short* wb = (const unsigned short*)wcat2;

    // ---- prefetch kg=0 H-frags (latency flies under stage+stats) ----
    s8b ahc[4];
#pragma unroll
    for (int mi = 0; mi < 4; ++mi)
        ahc[mi] = *(const s8b*)(xb + (size_t)((P0 >> 4) + mi) * 2048 + (size_t)lane * 8);

    // ---- widened stage+stats: lane = (c-half ch, p-pair pp); ushort2 reads ----
    // wave w owns c in [32w, 32w+32); lane covers p = {2pp, 2pp+1}, c-half ch.
    {
        const int ch = lane >> 5;            // 0..1
        const int pp = lane & 31;
        const int p0 = 2 * pp, p1 = p0 + 1;
        const int ub = (p0 >> 4) * 4 + w;    // unit (same for p0,p1)
        float s0 = 0.f, s20 = 0.f, s1 = 0.f, s21 = 0.f;
#pragma unroll
        for (int q = 0; q < 2; ++q) {
            unsigned short t0[8], t1[8];
            const int c8 = w * 32 + ch * 16 + q * 8;
#pragma unroll
            for (int j = 0; j < 8; ++j) {
                const ushort2 v = *(const ushort2*)(tb + (size_t)(c8 + j) * TNP + P0 + p0);
                t0[j] = v.x; t1[j] = v.y;
                const float f0 = bf2f(v.x), f1 = bf2f(v.y);
                s0 += f0; s20 += f0 * f0;
                s1 += f1; s21 += f1 * f1;
            }
            const int sq = ch * 2 + q;       // = (c8>>3)&3
            *(s8b*)&yfr[ub * 512 + (sq * 16 + (p0 & 15)) * 8] = *(const s8b*)t0;
            *(s8b*)&yfr[ub * 512 + (sq * 16 + (p1 & 15)) * 8] = *(const s8b*)t1;
        }
        sred[w * 2 + ch][p0] = make_float2(s0, s20);
        sred[w * 2 + ch][p1] = make_float2(s1, s21);
    }
    __syncthreads();
    if (t < PB) {
        float s = 0.f, s2 = 0.f;
#pragma unroll
        for (int g = 0; g < 8; ++g) {
            const float2 v = sred[g][t];
            s += v.x; s2 += v.y;
        }
        const float mu = s * (1.0f / 128.0f);
        const float var = s2 * (1.0f / 128.0f) - mu * mu;
        stats[t] = make_float2(mu, rsqrtf(var + TEPS));
    }
    __syncthreads();

    // ---- dual GEMM: Y-frags from yfr (LDS); H-frags reg-double-buffered ----
    const int dO = w * 32;
    const int dG = 128 + w * 32;

    f4 acc[4][4];   // ni 0..1 = outp(Y·W'), 2..3 = gl(H)
#pragma unroll
    for (int mi = 0; mi < 4; ++mi)
#pragma unroll
        for (int ni = 0; ni < 4; ++ni)
            acc[mi][ni] = (f4){0.f, 0.f, 0.f, 0.f};

#pragma unroll
    for (int kg = 0; kg < 4; ++kg) {
        s8b ahn[4];
        if (kg < 3) {
#pragma unroll
            for (int mi = 0; mi < 4; ++mi)
                ahn[mi] = *(const s8b*)(xb + (size_t)((P0 >> 4) + mi) * 2048
                                           + (kg + 1) * 512 + (size_t)lane * 8);
        }
        s8b bo[2], bg[2], ay[4];
#pragma unroll
        for (int nd = 0; nd < 2; ++nd) {
            bo[nd] = *(const s8b*)(wb + (dO + nd * 16 + lh) * TC + kg * 32 + lq * 8);
            bg[nd] = *(const s8b*)(wb + (dG + nd * 16 + lh) * TC + kg * 32 + lq * 8);
        }
#pragma unroll
        for (int mi = 0; mi < 4; ++mi)
            ay[mi] = *(const s8b*)&yfr[(mi * 4 + kg) * 512 + lane * 8];
#pragma unroll
        for (int mi = 0; mi < 4; ++mi)
#pragma unroll
            for (int nd = 0; nd < 2; ++nd) {
                acc[mi][nd]     = __builtin_amdgcn_mfma_f32_16x16x32_bf16(
                    ay[mi], bo[nd], acc[mi][nd], 0, 0, 0);
                acc[mi][2 + nd] = __builtin_amdgcn_mfma_f32_16x16x32_bf16(
                    ahc[mi], bg[nd], acc[mi][2 + nd], 0, 0, 0);
            }
        if (kg < 3) {
#pragma unroll
            for (int mi = 0; mi < 4; ++mi) ahc[mi] = ahn[mi];
        }
    }

    // ---- epilogue: out = (rs*G - rs*mu*S_d + Tb_d) * sigmoid(Gl + gl_b) ----
    float Sd[2], Tbd[2], glb[2];
#pragma unroll
    for (int nd = 0; nd < 2; ++nd) {
        const int d = w * 32 + nd * 16 + lh;
        Sd[nd]  = Svec[d];
        Tbd[nd] = Tbvec[d];
        glb[nd] = gl_b[d];
    }
#pragma unroll
    for (int mi = 0; mi < 4; ++mi)
#pragma unroll
        for (int nd = 0; nd < 2; ++nd) {
            const f4 G = acc[mi][nd];
            const f4 Gg = acc[mi][2 + nd];
            const int d = w * 32 + nd * 16 + lh;
#pragma unroll
            for (int r = 0; r < 4; ++r) {
                const int ploc = mi * 16 + lq * 4 + r;
                const float2 st = stats[ploc];
                const float o = st.y * G[r] - st.y * st.x * Sd[nd] + Tbd[nd];
                outb[(size_t)(P0 + ploc) * TC + d] = o * sigmoidf(Gg[r] + glb[nd]);
            }
        }
}

extern "C" void kernel_launch(void* const* d_in, const int* in_sizes, int n_in,
                              void* d_out, int out_size, void* d_ws, size_t ws_size,
                              hipStream_t stream)
{
    const float* act    = (const float*)d_in[0];
    const float* mask   = (const float*)d_in[1];
    const float* lnw    = (const float*)d_in[2];
    const float* lnb    = (const float*)d_in[3];
    const float* proj_w = (const float*)d_in[4];
    const float* proj_b = (const float*)d_in[5];
    const float* gate_w = (const float*)d_in[6];
    const float* gate_b = (const float*)d_in[7];
    const float* cnw    = (const float*)d_in[8];
    const float* cnb    = (const float*)d_in[9];
    const float* outp_w = (const float*)d_in[10];
    const float* outp_b = (const float*)d_in[11];
    const float* gl_w   = (const float*)d_in[12];
    const float* gl_b   = (const float*)d_in[13];

    __hip_bfloat16* lt   = (__hip_bfloat16*)d_ws;
    __hip_bfloat16* rt   = lt + (size_t)TC * TNP;
    __hip_bfloat16* xhp  = rt + (size_t)TC * TNP;
    __hip_bfloat16* trih = xhp + (size_t)TNP * TC;
    __hip_bfloat16* warr = trih + (size_t)TC * TNP;
    __hip_bfloat16* wcat2 = warr + 4 * 128 * TC;
    float* Svec  = (float*)(wcat2 + 2 * TC * TC);
    float* Tbvec = Svec + TC;
    float* out = (float*)d_out;

    k_wconv<<<384, 256, 0, stream>>>(proj_w, gate_w, outp_w, gl_w, cnw, warr, wcat2);
    k_sdt<<<1, 128, 0, stream>>>(outp_w, cnw, cnb, outp_b, Svec, Tbvec);
    k_ln<<<TNP / 64, 256, 0, stream>>>(act, lnw, lnb, xhp);
    k_proj<<<8192, 256, 0, stream>>>(xhp, mask, warr, proj_b, gate_b, lt, rt);
    k_tri_mfma<<<2048, 256, 0, stream>>>(lt, rt, trih);
    k_out_proj<<<TNP / PB, 256, 0, stream>>>(trih, xhp, wcat2, Svec, Tbvec,
                                             gl_b, out);
}

// Round 22
// 276.570 us; speedup vs baseline: 1.0535x; 1.0342x over previous
//
#include <hip/hip_runtime.h>
#include <hip/hip_bf16.h>

// Round 22: exact r17 restore (best: 278.6us). k_ln r17, k_proj r17 (8192 blocks,
// W reg-dbuf, tls alias), k_tri r10, k_out_proj r17 (ah prefetch/dbuf).
// ws: lt[C][NP] | rt[C][NP] | xhp (frag) | trih[C][NP] (bf16) | warr | wcat2 | S,Tb

constexpr int TN = 512;
constexpr int TC = 128;
constexpr int TNP = TN * TN;
constexpr float TEPS = 1e-5f;

typedef __attribute__((ext_vector_type(8))) short s8b;   // 8 bf16
typedef __attribute__((ext_vector_type(4))) float f4;    // 4 fp32

__device__ __forceinline__ float wredsum(float v) {
#pragma unroll
    for (int off = 32; off > 0; off >>= 1) v += __shfl_xor(v, off);
    return v;
}
__device__ __forceinline__ float sigmoidf(float x) { return 1.0f / (1.0f + __expf(-x)); }
__device__ __forceinline__ unsigned short bfbits(float f) {
    __hip_bfloat16 h = __float2bfloat16(f);
    return *reinterpret_cast<unsigned short*>(&h);
}
__device__ __forceinline__ float bf2f(unsigned short u) {
    return __uint_as_float(((unsigned int)u) << 16);
}

// frag-unit layout (xhp global, LDS tiles, warr): unit(g = p>>4, kg = c>>5)
// of 512 ushorts; slot = ((c>>3)&3)*16 + (p&15); elem = c&7.

// -------- weight pre-convert/rearrange (wcat2: cnw-folded outp | gl) --------
extern "C" __global__ __launch_bounds__(256)
void k_wconv(const float* __restrict__ pw, const float* __restrict__ gw,
             const float* __restrict__ ow, const float* __restrict__ glw,
             const float* __restrict__ cnw,
             __hip_bfloat16* __restrict__ warr, __hip_bfloat16* __restrict__ wcat2)
{
    const int idx = blockIdx.x * 256 + threadIdx.x;
    if (idx < 65536) {
        const int j = idx & 7;
        const int slot = (idx >> 3) & 63;
        const int kg = (idx >> 9) & 3;
        const int rg = (idx >> 11) & 7;
        const int nc = idx >> 14;
        const int lh = slot & 15, lq = slot >> 4;
        const int row = rg * 16 + lh;
        const int k = kg * 32 + lq * 8 + j;
        const float v = (row < 64) ? pw[(nc * 64 + row) * TC + k]
                                   : gw[(nc * 64 + (row - 64)) * TC + k];
        warr[idx] = __float2bfloat16(v);
    } else if (idx < 98304) {
        const int j = idx - 65536;
        if (j < 16384) {
            const int c = j & 127;
            wcat2[j] = __float2bfloat16(cnw[c] * ow[j]);   // W' = cnw ⊙ outp_w
        } else {
            wcat2[j] = __float2bfloat16(glw[j - 16384]);
        }
    }
}

// -------- S_d / Tb_d for the affine-folded LN --------
extern "C" __global__ __launch_bounds__(128)
void k_sdt(const float* __restrict__ ow, const float* __restrict__ cnw,
           const float* __restrict__ cnb, const float* __restrict__ outp_b,
           float* __restrict__ Svec, float* __restrict__ Tbvec)
{
    const int d = threadIdx.x;
    float S = 0.f, T = 0.f;
    for (int c = 0; c < TC; ++c) {
        const float w = ow[d * TC + c];
        S += cnw[c] * w;
        T += cnb[c] * w;
    }
    Svec[d] = S;
    Tbvec[d] = T + outp_b[d];
}

// -------- Kernel A1: LayerNorm -> xh_perm --------
extern "C" __global__ __launch_bounds__(256)
void k_ln(const float* __restrict__ act, const float* __restrict__ lnw,
          const float* __restrict__ lnb, __hip_bfloat16* __restrict__ xhp)
{
    __shared__ __align__(16) unsigned short t16[16 * 136];
    const int t = threadIdx.x, lane = t & 63, w = t >> 6;
    const int P0 = blockIdx.x * 64;
    const float2 wv = ((const float2*)lnw)[lane];
    const float2 bv = ((const float2*)lnb)[lane];
    unsigned short* xb = (unsigned short*)xhp;

    for (int r = 0; r < 4; ++r) {
#pragma unroll
        for (int q = 0; q < 4; ++q) {
            const int prow = w * 4 + q;
            const int p = P0 + r * 16 + prow;
            const float2 a = ((const float2*)(act + (size_t)p * TC))[lane];
            const float mu = wredsum(a.x + a.y) * (1.0f / 128.0f);
            const float d0 = a.x - mu, d1 = a.y - mu;
            const float var = wredsum(d0 * d0 + d1 * d1) * (1.0f / 128.0f);
            const float rs = rsqrtf(var + TEPS);
            ushort2 o;
            o.x = bfbits(d0 * rs * wv.x + bv.x);
            o.y = bfbits(d1 * rs * wv.y + bv.y);
            *(ushort2*)&t16[prow * 136 + lane * 2] = o;
        }
        __syncthreads();
        {
            const int kg = t >> 6, lq = (t >> 4) & 3, lh = t & 15;
            const s8b v = *(const s8b*)&t16[lh * 136 + kg * 32 + lq * 8];
            *(s8b*)(xb + (size_t)((P0 >> 4) + r) * 2048 + (size_t)t * 8) = v;
        }
        __syncthreads();
    }
}

// -------- Kernel A2: MFMA proj+gate GEMM; X in LDS, W reg-double-buffered ------
extern "C" __global__ __launch_bounds__(256)
void k_proj(const __hip_bfloat16* __restrict__ xhp, const float* __restrict__ mask,
            const __hip_bfloat16* __restrict__ warr,
            const float* __restrict__ proj_b, const float* __restrict__ gate_b,
            __hip_bfloat16* __restrict__ lt, __hip_bfloat16* __restrict__ rt)
{
    __shared__ __align__(16) unsigned short Xls[128 * TC];   // 32 KB, frag units
    __shared__ float msk[128];
    unsigned short* tls = Xls;   // 64x134 transpose tile aliased after MFMA

    const int t = threadIdx.x, lane = t & 63, w = t >> 6;
    const int lh = lane & 15, lq = lane >> 4;

    const int bid = blockIdx.x;
    const int work = (bid & 7) * 1024 + (bid >> 3);
    const int pt = work >> 2, dt = work & 3;
    const int P0 = pt * 128;

    const unsigned short* xb = (const unsigned short*)xhp;
    const unsigned short* wbc = (const unsigned short*)warr + (size_t)dt * 16384;

    if (t < 128) msk[t] = mask[P0 + t];

    const int wm = w >> 1, wn = w & 1;

    // stage X: 32 frag units (1 KB each), linear copy
#pragma unroll
    for (int s = 0; s < 8; ++s) {
        const int u = w * 8 + s;
        const size_t gu = ((size_t)(P0 >> 4) + (u >> 2)) * 4 + (u & 3);
        __builtin_amdgcn_global_load_lds(
            (const __attribute__((address_space(1))) unsigned*)(xb + gu * 512 + (size_t)lane * 8),
            (__attribute__((address_space(3))) unsigned*)&Xls[u * 512], 16, 0, 0);
    }

    // W-frags kg=0 issued before the barrier (fly during X-staging drain)
    s8b bc[4], bn[4];
#pragma unroll
    for (int nd = 0; nd < 2; ++nd) {
        bc[nd]     = *(const s8b*)(wbc + (size_t)(((wn * 2 + nd) * 4) + 0) * 512 + lane * 8);
        bc[2 + nd] = *(const s8b*)(wbc + (size_t)(((4 + wn * 2 + nd) * 4) + 0) * 512 + lane * 8);
    }
    __syncthreads();

    f4 acc[4][4];   // [mi][nd]: nd 0,1 = proj, 2,3 = gate
#pragma unroll
    for (int mi = 0; mi < 4; ++mi)
#pragma unroll
        for (int ni = 0; ni < 4; ++ni)
            acc[mi][ni] = (f4){0.f, 0.f, 0.f, 0.f};

#pragma unroll
    for (int kg = 0; kg < 4; ++kg) {
        if (kg < 3) {
#pragma unroll
            for (int nd = 0; nd < 2; ++nd) {
                bn[nd]     = *(const s8b*)(wbc + (size_t)(((wn * 2 + nd) * 4) + kg + 1) * 512 + lane * 8);
                bn[2 + nd] = *(const s8b*)(wbc + (size_t)(((4 + wn * 2 + nd) * 4) + kg + 1) * 512 + lane * 8);
            }
        }
        s8b af[4];
#pragma unroll
        for (int mi = 0; mi < 4; ++mi)
            af[mi] = *(const s8b*)&Xls[(((wm * 4 + mi) * 4) + kg) * 512 + lane * 8];
#pragma unroll
        for (int mi = 0; mi < 4; ++mi)
#pragma unroll
            for (int ni = 0; ni < 4; ++ni)
                acc[mi][ni] = __builtin_amdgcn_mfma_f32_16x16x32_bf16(
                    af[mi], bc[ni], acc[mi][ni], 0, 0, 0);
        if (kg < 3) {
#pragma unroll
            for (int ni = 0; ni < 4; ++ni) bc[ni] = bn[ni];
        }
    }
    __syncthreads();   // all Xls reads done before tls alias writes

    // epilogue: gate + transpose tile [64 d][134 p]
#pragma unroll
    for (int mi = 0; mi < 4; ++mi)
#pragma unroll
        for (int nd = 0; nd < 2; ++nd) {
            const int dl = wn * 32 + nd * 16 + lh;
            const float pbv = proj_b[dt * 64 + dl];
            const float gbv = gate_b[dt * 64 + dl];
            const f4 P = acc[mi][nd];
            const f4 G = acc[mi][2 + nd];
            const int pbase = wm * 64 + mi * 16 + lq * 4;
            float v[4];
#pragma unroll
            for (int r = 0; r < 4; ++r)
                v[r] = msk[pbase + r] * (P[r] + pbv) * sigmoidf(G[r] + gbv);
            ushort2 u01, u23;
            u01.x = bfbits(v[0]); u01.y = bfbits(v[1]);
            u23.x = bfbits(v[2]); u23.y = bfbits(v[3]);
            *(ushort2*)&tls[dl * 134 + pbase]     = u01;
            *(ushort2*)&tls[dl * 134 + pbase + 2] = u23;
        }
    __syncthreads();

    // readout: 64 d-rows x 128 p, ushort2-coalesced
    {
        __hip_bfloat16* dst0 = (dt < 2) ? lt + (size_t)(dt * 64) * TNP
                                        : rt + (size_t)((dt - 2) * 64) * TNP;
#pragma unroll
        for (int rr = 0; rr < 16; ++rr) {
            const int dl = w * 16 + rr;
            const ushort2 v = *(const ushort2*)&tls[dl * 134 + lane * 2];
            *(ushort2*)((unsigned short*)(dst0 + (size_t)dl * TNP) + P0 + lane * 2) = v;
        }
    }
}

// -------- Kernel B: per-c NT-GEMM (r10 single-stage version) --------
extern "C" __global__ __launch_bounds__(256)
void k_tri_mfma(const __hip_bfloat16* __restrict__ lt,
                const __hip_bfloat16* __restrict__ rt,
                __hip_bfloat16* __restrict__ trih)
{
    __shared__ __align__(16) char smem[128 * 136 * 2];
    __hip_bfloat16* Als = (__hip_bfloat16*)smem;
    __hip_bfloat16* Bls = (__hip_bfloat16*)(smem + 8192);
    unsigned short* Cls = (unsigned short*)smem;

    const int bid = blockIdx.x;
    const int work = (bid & 7) * 256 + (bid >> 3);
    const int c = work >> 4, tt = work & 15;
    const int i0 = (tt >> 2) * 128, j0 = (tt & 3) * 128;

    const int t = threadIdx.x;
    const int w = t >> 6, lane = t & 63;
    const int wm = w >> 1, wn = w & 1;
    const int lh = lane & 15, lq = lane >> 4;

    const size_t cbase = (size_t)c * TNP;
    const int srow = lane >> 2;
    const int scol = (lane & 3) * 8;

    f4 acc[4][4];
#pragma unroll
    for (int mi = 0; mi < 4; ++mi)
#pragma unroll
        for (int ni = 0; ni < 4; ++ni)
            acc[mi][ni] = (f4){0.f, 0.f, 0.f, 0.f};

    for (int k0 = 0; k0 < TN; k0 += 32) {
        __syncthreads();
#pragma unroll
        for (int s = 0; s < 2; ++s) {
            const int r0 = w * 32 + s * 16;
            const __hip_bfloat16* ga = lt + cbase + (size_t)(i0 + r0 + srow) * TN + k0 + scol;
            const __hip_bfloat16* gbp = rt + cbase + (size_t)(j0 + r0 + srow) * TN + k0 + scol;
            __builtin_amdgcn_global_load_lds(
                (const __attribute__((address_space(1))) unsigned*)ga,
                (__attribute__((address_space(3))) unsigned*)&Als[r0 * 32], 16, 0, 0);
            __builtin_amdgcn_global_load_lds(
                (const __attribute__((address_space(1))) unsigned*)gbp,
                (__attribute__((address_space(3))) unsigned*)&Bls[r0 * 32], 16, 0, 0);
        }
        __syncthreads();

        s8b afr[4], bfr[4];
#pragma unroll
        for (int mi = 0; mi < 4; ++mi)
            afr[mi] = *(const s8b*)&Als[(wm * 64 + mi * 16 + lh) * 32 + lq * 8];
#pragma unroll
        for (int ni = 0; ni < 4; ++ni)
            bfr[ni] = *(const s8b*)&Bls[(wn * 64 + ni * 16 + lh) * 32 + lq * 8];
#pragma unroll
        for (int mi = 0; mi < 4; ++mi)
#pragma unroll
            for (int ni = 0; ni < 4; ++ni)
                acc[mi][ni] = __builtin_amdgcn_mfma_f32_16x16x32_bf16(
                    afr[mi], bfr[ni], acc[mi][ni], 0, 0, 0);
    }

    __syncthreads();
#pragma unroll
    for (int mi = 0; mi < 4; ++mi)
#pragma unroll
        for (int ni = 0; ni < 4; ++ni) {
            const f4 v = acc[mi][ni];
            const int jl = wn * 64 + ni * 16 + lh;
#pragma unroll
            for (int r = 0; r < 4; ++r) {
                const int il = wm * 64 + mi * 16 + lq * 4 + r;
                Cls[il * 136 + jl] = bfbits(v[r]);
            }
        }
    __syncthreads();
    {
        unsigned short* ob = (unsigned short*)trih + cbase;
#pragma unroll
        for (int qq = 0; qq < 8; ++qq) {
            const int row = qq * 16 + (t >> 4);
            const int c16 = t & 15;
            const s8b v = *(const s8b*)&Cls[row * 136 + c16 * 8];
            *(s8b*)&ob[(size_t)(i0 + row) * TN + j0 + c16 * 8] = v;
        }
    }
}

// -------- Kernel C: affine-folded LN + MFMA (r17: ah prefetch/dbuf) ------
constexpr int PB = 64;

extern "C" __global__ __launch_bounds__(256)
void k_out_proj(const __hip_bfloat16* __restrict__ trih,
                const __hip_bfloat16* __restrict__ xhp,
                const __hip_bfloat16* __restrict__ wcat2,
                const float* __restrict__ Svec, const float* __restrict__ Tbvec,
                const float* __restrict__ gl_b,
                float* __restrict__ outb)
{
    __shared__ __align__(16) unsigned short yfr[PB * TC];   // 16 KB frag units
    __shared__ float2 sred[4][PB];                           // 2 KB partials
    __shared__ float2 stats[PB];                             // (mu, rs)

    const int t = threadIdx.x, lane = t & 63, w = t >> 6;
    const int lh = lane & 15, lq = lane >> 4;
    const int P0 = blockIdx.x * PB;
    const unsigned short* tb = (const unsigned short*)trih;
    const unsigned short* xb = (const unsigned short*)xhp;
    const unsigned short* wb = (const unsigned short*)wcat2;

    // ---- prefetch kg=0 H-frags (L3 latency flies under stage+stats) ----
    s8b ahc[4];
#pragma unroll
    for (int mi = 0; mi < 4; ++mi)
        ahc[mi] = *(const s8b*)(xb + (size_t)((P0 >> 4) + mi) * 2048 + (size_t)lane * 8);

    // ---- fused stage+stats: lane = p, wave w owns c in [32w,32w+32) ----
    {
        const int p = lane;
        const int ub = (p >> 4) * 4 + w;
        const int sl = p & 15;
        float s = 0.f, s2 = 0.f;
#pragma unroll
        for (int q = 0; q < 4; ++q) {
            unsigned short tmp[8];
#pragma unroll
            for (int j = 0; j < 8; ++j) {
                const int c = w * 32 + q * 8 + j;
                tmp[j] = tb[(size_t)c * TNP + P0 + p];
                const float f = bf2f(tmp[j]);
                s += f; s2 += f * f;
            }
            *(s8b*)&yfr[ub * 512 + (q * 16 + sl) * 8] = *(const s8b*)tmp;
        }
        sred[w][p] = make_float2(s, s2);
    }
    __syncthreads();
    if (t < PB) {
        float s = 0.f, s2 = 0.f;
#pragma unroll
        for (int g = 0; g < 4; ++g) {
            const float2 v = sred[g][t];
            s += v.x; s2 += v.y;
        }
        const float mu = s * (1.0f / 128.0f);
        const float var = s2 * (1.0f / 128.0f) - mu * mu;
        stats[t] = make_float2(mu, rsqrtf(var + TEPS));
    }
    __syncthreads();

    // ---- dual GEMM: Y-frags from yfr (LDS); H-frags reg-double-buffered ----
    const int dO = w * 32;
    const int dG = 128 + w * 32;

    f4 acc[4][4];   // ni 0..1 = outp(Y·W'), 2..3 = gl(H)
#pragma unroll
    for (int mi = 0; mi < 4; ++mi)
#pragma unroll
        for (int ni = 0; ni < 4; ++ni)
            acc[mi][ni] = (f4){0.f, 0.f, 0.f, 0.f};

#pragma unroll
    for (int kg = 0; kg < 4; ++kg) {
        s8b ahn[4];
        if (kg < 3) {
#pragma unroll
            for (int mi = 0; mi < 4; ++mi)
                ahn[mi] = *(const s8b*)(xb + (size_t)((P0 >> 4) + mi) * 2048
                                           + (kg + 1) * 512 + (size_t)lane * 8);
        }
        s8b bo[2], bg[2], ay[4];
#pragma unroll
        for (int nd = 0; nd < 2; ++nd) {
            bo[nd] = *(const s8b*)(wb + (dO + nd * 16 + lh) * TC + kg * 32 + lq * 8);
            bg[nd] = *(const s8b*)(wb + (dG + nd * 16 + lh) * TC + kg * 32 + lq * 8);
        }
#pragma unroll
        for (int mi = 0; mi < 4; ++mi)
            ay[mi] = *(const s8b*)&yfr[(mi * 4 + kg) * 512 + lane * 8];
#pragma unroll
        for (int mi = 0; mi < 4; ++mi)
#pragma unroll
            for (int nd = 0; nd < 2; ++nd) {
                acc[mi][nd]     = __builtin_amdgcn_mfma_f32_16x16x32_bf16(
                    ay[mi], bo[nd], acc[mi][nd], 0, 0, 0);
                acc[mi][2 + nd] = __builtin_amdgcn_mfma_f32_16x16x32_bf16(
                    ahc[mi], bg[nd], acc[mi][2 + nd], 0, 0, 0);
            }
        if (kg < 3) {
#pragma unroll
            for (int mi = 0; mi < 4; ++mi) ahc[mi] = ahn[mi];
        }
    }

    // ---- epilogue: out = (rs*G - rs*mu*S_d + Tb_d) * sigmoid(Gl + gl_b) ----
    float Sd[2], Tbd[2], glb[2];
#pragma unroll
    for (int nd = 0; nd < 2; ++nd) {
        const int d = w * 32 + nd * 16 + lh;
        Sd[nd]  = Svec[d];
        Tbd[nd] = Tbvec[d];
        glb[nd] = gl_b[d];
    }
#pragma unroll
    for (int mi = 0; mi < 4; ++mi)
#pragma unroll
        for (int nd = 0; nd < 2; ++nd) {
            const f4 G = acc[mi][nd];
            const f4 Gg = acc[mi][2 + nd];
            const int d = w * 32 + nd * 16 + lh;
#pragma unroll
            for (int r = 0; r < 4; ++r) {
                const int ploc = mi * 16 + lq * 4 + r;
                const float2 st = stats[ploc];
                const float o = st.y * G[r] - st.y * st.x * Sd[nd] + Tbd[nd];
                outb[(size_t)(P0 + ploc) * TC + d] = o * sigmoidf(Gg[r] + glb[nd]);
            }
        }
}

extern "C" void kernel_launch(void* const* d_in, const int* in_sizes, int n_in,
                              void* d_out, int out_size, void* d_ws, size_t ws_size,
                              hipStream_t stream)
{
    const float* act    = (const float*)d_in[0];
    const float* mask   = (const float*)d_in[1];
    const float* lnw    = (const float*)d_in[2];
    const float* lnb    = (const float*)d_in[3];
    const float* proj_w = (const float*)d_in[4];
    const float* proj_b = (const float*)d_in[5];
    const float* gate_w = (const float*)d_in[6];
    const float* gate_b = (const float*)d_in[7];
    const float* cnw    = (const float*)d_in[8];
    const float* cnb    = (const float*)d_in[9];
    const float* outp_w = (const float*)d_in[10];
    const float* outp_b = (const float*)d_in[11];
    const float* gl_w   = (const float*)d_in[12];
    const float* gl_b   = (const float*)d_in[13];

    __hip_bfloat16* lt   = (__hip_bfloat16*)d_ws;
    __hip_bfloat16* rt   = lt + (size_t)TC * TNP;
    __hip_bfloat16* xhp  = rt + (size_t)TC * TNP;
    __hip_bfloat16* trih = xhp + (size_t)TNP * TC;
    __hip_bfloat16* warr = trih + (size_t)TC * TNP;
    __hip_bfloat16* wcat2 = warr + 4 * 128 * TC;
    float* Svec  = (float*)(wcat2 + 2 * TC * TC);
    float* Tbvec = Svec + TC;
    float* out = (float*)d_out;

    k_wconv<<<384, 256, 0, stream>>>(proj_w, gate_w, outp_w, gl_w, cnw, warr, wcat2);
    k_sdt<<<1, 128, 0, stream>>>(outp_w, cnw, cnb, outp_b, Svec, Tbvec);
    k_ln<<<TNP / 64, 256, 0, stream>>>(act, lnw, lnb, xhp);
    k_proj<<<8192, 256, 0, stream>>>(xhp, mask, warr, proj_b, gate_b, lt, rt);
    k_tri_mfma<<<2048, 256, 0, stream>>>(lt, rt, trih);
    k_out_proj<<<TNP / PB, 256, 0, stream>>>(trih, xhp, wcat2, Svec, Tbvec,
                                             gl_b, out);
}